// Round 5
// baseline (329.246 us; speedup 1.0000x reference)
//
#include <hip/hip_runtime.h>
#include <stdint.h>

#define NG 4
#define NK 160
#define GD 128
#define ED 512
#define BB 16
#define TT 4096
#define NTOK (BB * TT)
#define KHALF 80                     // codes staged per LDS phase (40 KB)
static constexpr size_t ZSZ = (size_t)BB * ED * TT;           // 33554432

// d_out is FLOAT32. Layout: [0,ZSZ) z_q | [ZSZ] loss | codes after.
// ws: [0,4096) bsum f32 | [4096,4736) sc f32.

// ---------------- pass 1: codeword squared norms ----------------
__global__ void sc_kernel(const float* __restrict__ cb, float* __restrict__ sc) {
  int i = blockIdx.x * blockDim.x + threadIdx.x;
  if (i >= NG * NK) return;
  const float* c = cb + (size_t)i * GD;
  float s = 0.f;
  for (int d = 0; d < GD; ++d) s = fmaf(c[d], c[d], s);
  sc[i] = s;
}

// ---------------- pass 2: fused argmin + z_q + codes + loss partials ------
// One group per block; codebook staged in LDS (two 40 KB halves) and read as
// wave-uniform broadcast ds_read_b128. x[128] held in VGPRs, liveness forced
// through the k-loop by per-iteration keep-alive asm.
__global__ __launch_bounds__(256, 3) void vq_kernel(const float* __restrict__ xin,
                                                    const float* __restrict__ cb,
                                                    const float* __restrict__ sc,
                                                    float* __restrict__ out,
                                                    float* __restrict__ bsum) {
  __shared__ float cbs[KHALF * GD];                       // 40 KB

  const int g = (int)(blockIdx.x >> 8);                   // 256 blocks per group
  const int n = (int)((blockIdx.x & 255) * 256 + threadIdx.x);
  const int b = n >> 12;
  const int t = n & 4095;

  // Load x once (coalesced: lane ~ t at fixed channel).
  const float* xp = xin + ((size_t)b * ED + (size_t)g * GD) * TT + t;
  float x[GD];
#pragma unroll
  for (int d = 0; d < GD; ++d) x[d] = xp[(size_t)d * TT];

  float sx = 0.f;
#pragma unroll
  for (int d = 0; d < GD; ++d) sx = fmaf(x[d], x[d], sx);

  const float4* cbg4 = (const float4*)(cb + (size_t)g * NK * GD);
  const float* scg = sc + g * NK;

  float best = 3.4e38f;
  int bik = 0;

  for (int half = 0; half < 2; ++half) {
    // ---- stage 80 codes (40 KB) into LDS, coalesced ----
    __syncthreads();                                      // prev phase done reading
    {
      const float4* src = cbg4 + (size_t)half * KHALF * (GD / 4);
      float4* dst = (float4*)cbs;
#pragma unroll
      for (int i = 0; i < (KHALF * GD / 4) / 256; ++i)    // 10 iters
        dst[i * 256 + threadIdx.x] = src[i * 256 + threadIdx.x];
    }
    __syncthreads();

    // ---- scan the staged codes ----
    for (int k0 = 0; k0 < KHALF; k0 += 4) {
      // force x[*] to stay register-resident across the loop
#pragma unroll
      for (int d = 0; d < GD; ++d) asm volatile("" : "+v"(x[d]));

      const float4* c0 = (const float4*)(cbs + (size_t)(k0 + 0) * GD);
      const float4* c1 = (const float4*)(cbs + (size_t)(k0 + 1) * GD);
      const float4* c2 = (const float4*)(cbs + (size_t)(k0 + 2) * GD);
      const float4* c3 = (const float4*)(cbs + (size_t)(k0 + 3) * GD);
      float a0 = 0.f, a1 = 0.f, a2 = 0.f, a3 = 0.f;
#pragma unroll
      for (int d4 = 0; d4 < GD / 4; ++d4) {
        float4 v0 = c0[d4], v1 = c1[d4], v2 = c2[d4], v3 = c3[d4];
        a0 = fmaf(x[4 * d4 + 0], v0.x, a0);
        a0 = fmaf(x[4 * d4 + 1], v0.y, a0);
        a0 = fmaf(x[4 * d4 + 2], v0.z, a0);
        a0 = fmaf(x[4 * d4 + 3], v0.w, a0);
        a1 = fmaf(x[4 * d4 + 0], v1.x, a1);
        a1 = fmaf(x[4 * d4 + 1], v1.y, a1);
        a1 = fmaf(x[4 * d4 + 2], v1.z, a1);
        a1 = fmaf(x[4 * d4 + 3], v1.w, a1);
        a2 = fmaf(x[4 * d4 + 0], v2.x, a2);
        a2 = fmaf(x[4 * d4 + 1], v2.y, a2);
        a2 = fmaf(x[4 * d4 + 2], v2.z, a2);
        a2 = fmaf(x[4 * d4 + 3], v2.w, a2);
        a3 = fmaf(x[4 * d4 + 0], v3.x, a3);
        a3 = fmaf(x[4 * d4 + 1], v3.y, a3);
        a3 = fmaf(x[4 * d4 + 2], v3.z, a3);
        a3 = fmaf(x[4 * d4 + 3], v3.w, a3);
      }
      const int kb = half * KHALF + k0;
      float d0 = (sx + scg[kb + 0]) - 2.0f * a0;          // ref formula order
      float d1 = (sx + scg[kb + 1]) - 2.0f * a1;
      float d2 = (sx + scg[kb + 2]) - 2.0f * a2;
      float d3 = (sx + scg[kb + 3]) - 2.0f * a3;
      if (d0 < best) { best = d0; bik = kb + 0; }         // first-min tie-break
      if (d1 < best) { best = d1; bik = kb + 1; }
      if (d2 < best) { best = d2; bik = kb + 2; }
      if (d3 < best) { best = d3; bik = kb + 3; }
    }
  }

  // codes_out[b, g, t] (float-encoded int)
  out[ZSZ + 1 + ((size_t)b * NG + g) * TT + t] = (float)bik;

  // z_q_out[b, g*128+d, t] = codebook[g, bik, d] (gather from global, L2-hot)
  const float4* cw = cbg4 + (size_t)bik * (GD / 4);
  float* zp = out + ((size_t)b * ED + (size_t)g * GD) * TT + t;
#pragma unroll
  for (int d4 = 0; d4 < GD / 4; ++d4) {
    float4 v = cw[d4];
    zp[(size_t)(4 * d4 + 0) * TT] = v.x;
    zp[(size_t)(4 * d4 + 1) * TT] = v.y;
    zp[(size_t)(4 * d4 + 2) * TT] = v.z;
    zp[(size_t)(4 * d4 + 3) * TT] = v.w;
  }

  // loss partial: best == ||x - c_best||^2; deterministic wave reduce,
  // one partial per wave -> bsum[block*4 + wave], 4096 total.
  float s = best;
#pragma unroll
  for (int off = 32; off > 0; off >>= 1) s += __shfl_down(s, off, 64);
  if ((threadIdx.x & 63) == 0)
    bsum[(size_t)blockIdx.x * 4 + (threadIdx.x >> 6)] = s;
}

// ---------------- pass 3: loss ----------------
__global__ __launch_bounds__(64) void loss_kernel(const float* __restrict__ bsum,
                                                  float* __restrict__ out) {
  float s = 0.f;
  for (int j = 0; j < 64; ++j) s += bsum[threadIdx.x + 64 * j];
#pragma unroll
  for (int off = 32; off > 0; off >>= 1) s += __shfl_down(s, off, 64);
  if (threadIdx.x == 0)
    out[ZSZ] = 1.25f * s / (float)ZSZ;
}

extern "C" void kernel_launch(void* const* d_in, const int* in_sizes, int n_in,
                              void* d_out, int out_size, void* d_ws, size_t ws_size,
                              hipStream_t stream) {
  const float* xin = (const float*)d_in[0];
  const float* cb  = (const float*)d_in[1];
  float* out  = (float*)d_out;
  float* bsum = (float*)d_ws;        // 4096 per-wave partial sums
  float* sc   = bsum + 4096;         // 640 codeword norms

  sc_kernel<<<10, 64, 0, stream>>>(cb, sc);
  vq_kernel<<<1024, 256, 0, stream>>>(xin, cb, sc, out, bsum);
  loss_kernel<<<1, 64, 0, stream>>>(bsum, out);
}